// Round 13
// baseline (113.791 us; speedup 1.0000x reference)
//
#include <hip/hip_runtime.h>
#include <hip/hip_bf16.h>
#include <math.h>

using f32x4 = __attribute__((ext_vector_type(4))) float;
using s16x8 = __attribute__((ext_vector_type(8))) short;
using s16x4 = __attribute__((ext_vector_type(4))) short;

#define LOG2E 1.44269504f

__device__ __forceinline__ unsigned short f2bf(float f) {
  unsigned int u = __builtin_bit_cast(unsigned int, f);
  u += 0x7FFFu + ((u >> 16) & 1u);
  return (unsigned short)(u >> 16);
}
__device__ __forceinline__ float lrelu(float v) { return v > 0.f ? v : 0.01f * v; }

__device__ __forceinline__ unsigned packbf(float lo, float hi) {
  return __builtin_amdgcn_perm(__builtin_bit_cast(unsigned, hi),
                               __builtin_bit_cast(unsigned, lo), 0x07060302u);
}
__device__ __forceinline__ float redsum_lh(float x) {
  x += __shfl_xor(x, 16);
  x += __shfl_xor(x, 32);
  return x;
}

#define GLL16(src, dst)                                                        \
  __builtin_amdgcn_global_load_lds(                                            \
      (const __attribute__((address_space(1))) void*)(src),                    \
      (__attribute__((address_space(3))) void*)(dst), 16, 0, 0)

// ---------------------------------------------------------------------------
// Kernel 1: x1t[n][c], x2t[n][c] (x2 pre-scaled by log2e), x3[c][n] (bf16)
// grid 512 (b*128 + nchunk32), block 256.
// Fixes vs R12: Wt [3][64][64] XOR-swizzled (kills 64-way write conflict),
// float4 sX reads in the FMA loop (8 b32 -> 2 b128 per k).
// ---------------------------------------------------------------------------
__global__ __launch_bounds__(256) void k1_conv3(
    const float* __restrict__ x,
    const float* __restrict__ W1, const float* __restrict__ b1,
    const float* __restrict__ W2, const float* __restrict__ b2,
    const float* __restrict__ W3, const float* __restrict__ b3,
    unsigned short* __restrict__ x1t, unsigned short* __restrict__ x2t,
    unsigned short* __restrict__ x3) {
  __shared__ float Wt[3][64][64];           // Wt[w][k][c ^ (k&31)] = W[c][k]
  __shared__ alignas(16) float sX[64][36];
  __shared__ float sB[64][33];
  const int t = threadIdx.x;
  const int b = blockIdx.x >> 7;
  const int n0 = (blockIdx.x & 127) << 5;

  const float* Ws[3] = {W1, W2, W3};
  for (int e = t; e < 12288; e += 256) {
    const int w = e >> 12, idx = e & 4095;
    const int k = idx & 63, c = idx >> 6;
    Wt[w][k][c ^ (k & 31)] = Ws[w][idx];    // banks spread by k -> conflict-free
  }
#pragma unroll
  for (int r = 0; r < 2; ++r) {
    const int idx = t + r * 256;
    const int k = idx >> 3, q = idx & 7;
    *(float4*)&sX[k][q * 4] = *(const float4*)(x + ((size_t)b * 64 + k) * 4096 + n0 + q * 4);
  }
  __syncthreads();

  const int c = t & 63, g = t >> 6;
  float y1[8], y2[8], y3[8];
  const float bb1 = b1[c], bb2 = b2[c], bb3 = b3[c];
#pragma unroll
  for (int j = 0; j < 8; ++j) { y1[j] = bb1; y2[j] = bb2; y3[j] = bb3; }

  for (int k = 0; k < 64; ++k) {
    const int cx = c ^ (k & 31);
    const float w1 = Wt[0][k][cx], w2 = Wt[1][k][cx], w3 = Wt[2][k][cx];
    const float4 xv0 = *(const float4*)&sX[k][g * 8];
    const float4 xv1 = *(const float4*)&sX[k][g * 8 + 4];
#pragma unroll
    for (int j = 0; j < 4; ++j) {
      const float xa = ((const float*)&xv0)[j], xb = ((const float*)&xv1)[j];
      y1[j] = __builtin_fmaf(w1, xa, y1[j]);
      y2[j] = __builtin_fmaf(w2, xa, y2[j]);
      y3[j] = __builtin_fmaf(w3, xa, y3[j]);
      y1[j + 4] = __builtin_fmaf(w1, xb, y1[j + 4]);
      y2[j + 4] = __builtin_fmaf(w2, xb, y2[j + 4]);
      y3[j + 4] = __builtin_fmaf(w3, xb, y3[j + 4]);
    }
  }
#pragma unroll
  for (int j = 0; j < 8; ++j) {
    const size_t n = (size_t)n0 + g * 8 + j;
    x1t[((size_t)b * 4096 + n) * 64 + c] = f2bf(lrelu(y1[j]));
    x2t[((size_t)b * 4096 + n) * 64 + c] = f2bf(lrelu(y2[j]) * LOG2E);
    sB[c][g * 8 + j] = lrelu(y3[j]);
  }
  __syncthreads();
  {
    const int c2 = t >> 2, q = t & 3;
    s16x8 v;
#pragma unroll
    for (int jj = 0; jj < 8; ++jj) v[jj] = (short)f2bf(sB[c2][q * 8 + jj]);
    *(s16x8*)(x3 + ((size_t)b * 64 + c2) * 4096 + n0 + q * 8) = v;
  }
}

// ---------------------------------------------------------------------------
// Kernel 2: flash attention. K direct-to-register (coalesced global), V via
// wave-private dbuf LDS in interleaved-quad layout; transpose-free PV; no
// barriers and no cross-lane ops in the loop; one manual vmcnt(4)/step.
// grid 256 = (b, mtile64). block 1024 = 16 waves = msub(2: 32m) x split(8: 512n).
// 16 steps x 32n (2 x 16n subs). LDS: V staging 16x8KB=131072 | W4 @131072 |
// sL @148480. Epilogue overlays staging with cO [16][32m][64c] XOR'd (128KB).
// ---------------------------------------------------------------------------
#define W4OFF 131072
#define SLOFF 148480
#define SMSZ 150528

__global__ __launch_bounds__(1024, 4) void k2_attn_fused(
    const unsigned short* __restrict__ x1t,
    const unsigned short* __restrict__ x2t,
    const unsigned short* __restrict__ x3,
    const float* __restrict__ W4, const float* __restrict__ b4,
    const float* __restrict__ x, float* __restrict__ out) {
  __shared__ __align__(16) char SM[SMSZ];
  char* smB = (char*)SM;

  const int t = threadIdx.x;
  const int wave = t >> 6, lane = t & 63;
  const int l15 = lane & 15, lh = lane >> 4;
  const int msub = wave & 1, split = wave >> 1;
  const int b = blockIdx.x >> 6;
  const int m0 = (blockIdx.x & 63) << 6;
  const int nb = split * 512;

  const char* x1B = (const char*)(x1t + (size_t)b * 4096 * 64); // [n][c] 128B rows
  const char* x3B = (const char*)(x3 + (size_t)b * 64 * 4096);  // [c][n] 8192B rows
  const unsigned short* x2b = x2t + (size_t)b * 4096 * 64;

  { // W4 -> LDS transposed (disjoint region)
    float* Wt4 = (float*)(smB + W4OFF);
    for (int e = t; e < 4096; e += 1024) Wt4[(e & 63) * 68 + (e >> 6)] = W4[e];
  }

  // wave-private V double buffer (2 x 4KB); each 4KB = 2 sub-tiles (16n) of 2KB
  char* vbase = smB + wave * 8192;
  const char* vsrc = x3B + (size_t)lane * 8192; // GLL: lane -> channel row
  // V read offset: value V[c=s*16+l15][n = lh*4+e] at sub + ((lh>>1)*4+s)*256
  //                + l15*16 + (lh&1)*8   (b64)
  const int vro = (lh >> 1) * 1024 + l15 * 16 + (lh & 1) * 8;

  // K direct loads: A-frag row base
  const char* kbase = x1B + (size_t)l15 * 128 + lh * 16;

  // Q fragments (B-operand), persistent: 2 groups of 16 m
  s16x8 qf[2][2];
#pragma unroll
  for (int q2 = 0; q2 < 2; ++q2) {
    const unsigned short* qp = x2b + (size_t)(m0 + msub * 32 + q2 * 16 + l15) * 64 + lh * 8;
    qf[q2][0] = *(const s16x8*)qp;
    qf[q2][1] = *(const s16x8*)(qp + 32);
  }

  f32x4 O[2][4];
#pragma unroll
  for (int q2 = 0; q2 < 2; ++q2)
#pragma unroll
    for (int s = 0; s < 4; ++s) O[q2][s] = (f32x4){0.f, 0.f, 0.f, 0.f};
  float l_part[2] = {0.f, 0.f};

  // prologue: V(0) -> buf0 (4 GLL), K(0) -> set A
  {
    const int nt = nb;
    GLL16(vsrc + (size_t)(nt + 0) * 2, vbase);
    GLL16(vsrc + (size_t)(nt + 8) * 2, vbase + 1024);
    GLL16(vsrc + (size_t)(nt + 16) * 2, vbase + 2048);
    GLL16(vsrc + (size_t)(nt + 24) * 2, vbase + 3072);
  }
  s16x8 kA0, kA1, kA2, kA3, kB0, kB1, kB2, kB3;
  {
    const char* kr = kbase + (size_t)nb * 128;
    kA0 = *(const s16x8*)kr;
    kA1 = *(const s16x8*)(kr + 64);
    kA2 = *(const s16x8*)(kr + 2048);
    kA3 = *(const s16x8*)(kr + 2048 + 64);
  }

#define STEP(J, K0, K1, K2, K3, N0, N1, N2, N3)                                \
  {                                                                            \
    const int p = (J) & 1;                                                     \
    asm volatile("s_waitcnt vmcnt(4)" ::: "memory"); /* V(J) staged */         \
    __builtin_amdgcn_sched_barrier(0);                                         \
    if ((J) < 15) { /* issue V(J+1) then K(J+1): order fixed by sched_barrier */\
      const int nt1 = nb + ((J) + 1) * 32;                                     \
      char* vd = vbase + (p ^ 1) * 4096;                                       \
      GLL16(vsrc + (size_t)(nt1 + 0) * 2, vd);                                 \
      GLL16(vsrc + (size_t)(nt1 + 8) * 2, vd + 1024);                          \
      GLL16(vsrc + (size_t)(nt1 + 16) * 2, vd + 2048);                         \
      GLL16(vsrc + (size_t)(nt1 + 24) * 2, vd + 3072);                         \
      __builtin_amdgcn_sched_barrier(0);                                       \
      const char* kr = kbase + (size_t)nt1 * 128;                              \
      N0 = *(const s16x8*)kr;                                                  \
      N1 = *(const s16x8*)(kr + 64);                                           \
      N2 = *(const s16x8*)(kr + 2048);                                         \
      N3 = *(const s16x8*)(kr + 2048 + 64);                                    \
    }                                                                          \
    const char* vp = vbase + p * 4096;                                         \
    s16x8 vf[4];                                                               \
    _Pragma("unroll") for (int s = 0; s < 4; ++s) {                            \
      const s16x4 ve = *(const s16x4*)(vp + vro + s * 256);                    \
      const s16x4 vo = *(const s16x4*)(vp + 2048 + vro + s * 256);             \
      _Pragma("unroll") for (int e = 0; e < 4; ++e) {                          \
        vf[s][e] = ve[e];                                                      \
        vf[s][e + 4] = vo[e];                                                  \
      }                                                                        \
    }                                                                          \
    _Pragma("unroll") for (int q2 = 0; q2 < 2; ++q2) {                         \
      f32x4 ze = {0.f, 0.f, 0.f, 0.f};                                         \
      ze = __builtin_amdgcn_mfma_f32_16x16x32_bf16(K0, qf[q2][0], ze, 0, 0, 0);\
      ze = __builtin_amdgcn_mfma_f32_16x16x32_bf16(K1, qf[q2][1], ze, 0, 0, 0);\
      f32x4 zo = {0.f, 0.f, 0.f, 0.f};                                         \
      zo = __builtin_amdgcn_mfma_f32_16x16x32_bf16(K2, qf[q2][0], zo, 0, 0, 0);\
      zo = __builtin_amdgcn_mfma_f32_16x16x32_bf16(K3, qf[q2][1], zo, 0, 0, 0);\
      const float e0 = __builtin_amdgcn_exp2f(ze[0]);                          \
      const float e1 = __builtin_amdgcn_exp2f(ze[1]);                          \
      const float e2 = __builtin_amdgcn_exp2f(ze[2]);                          \
      const float e3 = __builtin_amdgcn_exp2f(ze[3]);                          \
      const float o0 = __builtin_amdgcn_exp2f(zo[0]);                          \
      const float o1 = __builtin_amdgcn_exp2f(zo[1]);                          \
      const float o2 = __builtin_amdgcn_exp2f(zo[2]);                          \
      const float o3 = __builtin_amdgcn_exp2f(zo[3]);                          \
      l_part[q2] += ((e0 + e1) + (e2 + e3)) + ((o0 + o1) + (o2 + o3));         \
      int4 pw = {(int)packbf(e0, e1), (int)packbf(e2, e3),                     \
                 (int)packbf(o0, o1), (int)packbf(o2, o3)};                    \
      s16x8 pf = __builtin_bit_cast(s16x8, pw);                                \
      _Pragma("unroll") for (int s = 0; s < 4; ++s)                            \
        O[q2][s] = __builtin_amdgcn_mfma_f32_16x16x32_bf16(vf[s], pf,          \
                                                           O[q2][s], 0, 0, 0);\
    }                                                                          \
  }

#pragma unroll
  for (int jp = 0; jp < 8; ++jp) {
    STEP(2 * jp, kA0, kA1, kA2, kA3, kB0, kB1, kB2, kB3);
    STEP(2 * jp + 1, kB0, kB1, kB2, kB3, kA0, kA1, kA2, kA3);
  }
#undef STEP

  // ---- epilogue: publish fp32 partials over dead staging (XOR'd, no pad)
  __syncthreads(); // all main loops done (also drains counters)
  float* sLf = (float*)(smB + SLOFF); // [16][32]
#pragma unroll
  for (int q2 = 0; q2 < 2; ++q2) {
    const float l = redsum_lh(l_part[q2]);
    const int m32 = q2 * 16 + l15;
    if (lh == 0) sLf[wave * 32 + m32] = l;
#pragma unroll
    for (int s = 0; s < 4; ++s) {
      const int cb = s * 64 + lh * 16; // byte col of f32x4 (c = s*16+lh*4)
      *(f32x4*)(smB + wave * 8192 + m32 * 256 + (cb ^ ((m32 & 7) << 4))) = O[q2][s];
    }
  }
  __syncthreads();

  // ---- merge 8 splits: thread -> m=t&63, c-quad cq=t>>6
  const int mloc = t & 63, cq = t >> 6;
  const int msub2 = mloc >> 5, m32b = mloc & 31;
  const int rb = m32b * 256 + ((cq * 16) ^ ((m32b & 7) << 4));
  float den = 0.f, num[4] = {0.f, 0.f, 0.f, 0.f};
#pragma unroll
  for (int s2 = 0; s2 < 8; ++s2) {
    const int w = s2 * 2 + msub2;
    den += sLf[w * 32 + m32b];
    const f32x4 cv = *(const f32x4*)(smB + w * 8192 + rb);
#pragma unroll
    for (int jj = 0; jj < 4; ++jj) num[jj] += cv[jj];
  }
  const float inv = 1.f / den;
  __syncthreads(); // cO reads done -> overlay attnS
  float* attnS = (float*)smB; // [64][65]
#pragma unroll
  for (int jj = 0; jj < 4; ++jj) attnS[(cq * 4 + jj) * 65 + mloc] = num[jj] * inv;
  __syncthreads();

  // ---- conv4 + lrelu + residual
  const float* Wt4 = (const float*)(smB + W4OFF); // [64][68]
  const int co0 = cq * 4;
  float acc[4];
#pragma unroll
  for (int ci = 0; ci < 4; ++ci) acc[ci] = b4[co0 + ci];
  for (int k = 0; k < 64; ++k) {
    const float a = attnS[k * 65 + mloc];
    const float4 wv = *(const float4*)&Wt4[k * 68 + co0];
#pragma unroll
    for (int ci = 0; ci < 4; ++ci)
      acc[ci] = __builtin_fmaf(((const float*)&wv)[ci], a, acc[ci]);
  }
#pragma unroll
  for (int ci = 0; ci < 4; ++ci) {
    const size_t idx = ((size_t)b * 64 + co0 + ci) * 4096 + m0 + mloc;
    out[idx] = lrelu(acc[ci]) + x[idx];
  }
}

extern "C" void kernel_launch(void* const* d_in, const int* in_sizes, int n_in,
                              void* d_out, int out_size, void* d_ws, size_t ws_size,
                              hipStream_t stream) {
  const float* x = (const float*)d_in[0];
  const float* W1 = (const float*)d_in[1];
  const float* b1 = (const float*)d_in[2];
  const float* W2 = (const float*)d_in[3];
  const float* b2 = (const float*)d_in[4];
  const float* W3 = (const float*)d_in[5];
  const float* b3 = (const float*)d_in[6];
  const float* W4 = (const float*)d_in[7];
  const float* b4 = (const float*)d_in[8];
  float* out = (float*)d_out;

  const size_t planes = (size_t)4 * 4096 * 64; // 1M bf16 elems each
  unsigned short* x1t = (unsigned short*)d_ws;
  unsigned short* x2t = x1t + planes;
  unsigned short* x3 = x2t + planes;

  hipLaunchKernelGGL(k1_conv3, dim3(512), dim3(256), 0, stream,
                     x, W1, b1, W2, b2, W3, b3, x1t, x2t, x3);
  hipLaunchKernelGGL(k2_attn_fused, dim3(256), dim3(1024), 0, stream,
                     x1t, x2t, x3, W4, b4, x, out);
}

// Round 14
// 78.577 us; speedup vs baseline: 1.4482x; 1.4482x over previous
//
#include <hip/hip_runtime.h>
#include <hip/hip_bf16.h>
#include <math.h>

using f32x4 = __attribute__((ext_vector_type(4))) float;
using s16x8 = __attribute__((ext_vector_type(8))) short;
using s16x4 = __attribute__((ext_vector_type(4))) short;

#define LOG2E 1.44269504f

__device__ __forceinline__ unsigned short f2bf(float f) {
  unsigned int u = __builtin_bit_cast(unsigned int, f);
  u += 0x7FFFu + ((u >> 16) & 1u);
  return (unsigned short)(u >> 16);
}
__device__ __forceinline__ float lrelu(float v) { return v > 0.f ? v : 0.01f * v; }

// pack two f32 -> one u32 of 2 bf16 (truncation; bias cancels in softmax ratio)
__device__ __forceinline__ unsigned packbf(float lo, float hi) {
  return __builtin_amdgcn_perm(__builtin_bit_cast(unsigned, hi),
                               __builtin_bit_cast(unsigned, lo), 0x07060302u);
}
__device__ __forceinline__ float redsum_lh(float x) {
  x += __shfl_xor(x, 16);
  x += __shfl_xor(x, 32);
  return x;
}

#define GLL16(src, dst)                                                        \
  __builtin_amdgcn_global_load_lds(                                            \
      (const __attribute__((address_space(1))) void*)(src),                    \
      (__attribute__((address_space(3))) void*)(dst), 16, 0, 0)

// ---------------------------------------------------------------------------
// Kernel 0: WT[w][k][c] = W_w[c][k]  (3x64x64 f32 into ws). grid 3, block 256.
// ---------------------------------------------------------------------------
__global__ __launch_bounds__(256) void k0_wt(const float* __restrict__ W1,
                                             const float* __restrict__ W2,
                                             const float* __restrict__ W3,
                                             float* __restrict__ WT) {
  __shared__ float s[64][65];
  const float* Ws[3] = {W1, W2, W3};
  const int w = blockIdx.x, t = threadIdx.x;
  for (int e = t; e < 4096; e += 256) s[e >> 6][e & 63] = Ws[w][e]; // s[c][k]
  __syncthreads();
  for (int e = t; e < 4096; e += 256) WT[w * 4096 + e] = s[e & 63][e >> 6];
}

// ---------------------------------------------------------------------------
// Kernel 1: x1t[n][c], x2t[n][c] (x2 pre-scaled by log2e), x3[c][n] (bf16).
// grid 512 (b*128 + nchunk32), block 256. W read DIRECT from global WT
// (coalesced 256B rows, L2-hot) — no W LDS, no staging barrier.
// ---------------------------------------------------------------------------
__global__ __launch_bounds__(256) void k1_conv3(
    const float* __restrict__ x, const float* __restrict__ WT,
    const float* __restrict__ b1, const float* __restrict__ b2,
    const float* __restrict__ b3,
    unsigned short* __restrict__ x1t, unsigned short* __restrict__ x2t,
    unsigned short* __restrict__ x3) {
  __shared__ float sB[64][33];
  const int t = threadIdx.x;
  const int b = blockIdx.x >> 7;
  const int n0 = (blockIdx.x & 127) << 5;
  const int c = t & 63, g = t >> 6;

  float y1[8], y2[8], y3[8];
  const float bb1 = b1[c], bb2 = b2[c], bb3 = b3[c];
#pragma unroll
  for (int j = 0; j < 8; ++j) { y1[j] = bb1; y2[j] = bb2; y3[j] = bb3; }

  const float* xb = x + ((size_t)b * 64) * 4096 + n0 + g * 8;
  const float* w1p = WT + c;
  const float* w2p = WT + 4096 + c;
  const float* w3p = WT + 8192 + c;
#pragma unroll 4
  for (int k = 0; k < 64; ++k) {
    const float w1 = w1p[k * 64], w2 = w2p[k * 64], w3 = w3p[k * 64];
    const float4 xv0 = *(const float4*)(xb + (size_t)k * 4096);
    const float4 xv1 = *(const float4*)(xb + (size_t)k * 4096 + 4);
#pragma unroll
    for (int j = 0; j < 4; ++j) {
      const float xa = ((const float*)&xv0)[j], xb2 = ((const float*)&xv1)[j];
      y1[j] = __builtin_fmaf(w1, xa, y1[j]);
      y2[j] = __builtin_fmaf(w2, xa, y2[j]);
      y3[j] = __builtin_fmaf(w3, xa, y3[j]);
      y1[j + 4] = __builtin_fmaf(w1, xb2, y1[j + 4]);
      y2[j + 4] = __builtin_fmaf(w2, xb2, y2[j + 4]);
      y3[j + 4] = __builtin_fmaf(w3, xb2, y3[j + 4]);
    }
  }
#pragma unroll
  for (int j = 0; j < 8; ++j) {
    const size_t n = (size_t)n0 + g * 8 + j;
    x1t[((size_t)b * 4096 + n) * 64 + c] = f2bf(lrelu(y1[j]));
    x2t[((size_t)b * 4096 + n) * 64 + c] = f2bf(lrelu(y2[j]) * LOG2E);
    sB[c][g * 8 + j] = lrelu(y3[j]);
  }
  __syncthreads();
  {
    const int c2 = t >> 2, q = t & 3;
    s16x8 v;
#pragma unroll
    for (int jj = 0; jj < 8; ++jj) v[jj] = (short)f2bf(sB[c2][q * 8 + jj]);
    *(s16x8*)(x3 + ((size_t)b * 64 + c2) * 4096 + n0 + q * 8) = v;
  }
}

// ---------------------------------------------------------------------------
// Kernel 2: flash attention (no-max exp2), m=128 per block for 4x staging
// reuse. grid 128 = (b:4, mtile:32). block 1024 = 16 waves = split(4: 1024n)
// x msub(4: 32m). 32 steps x 32n; split-shared dbuf K/V (R10 layouts); ONE
// barrier/step with full-step prefetch shadow (GLLs issued at step top into
// buf p^1; end-barrier's implicit vmcnt(0) makes all staging visible).
// Transpose-free PV (R12-proven k-permutation). Epilogue: cO publish (R13
// swizzle) -> 4-split merge -> conv4+residual, m=128.
// LDS: staging 4x16KB=64KB inside cO region [16][8KB]=131072 | W4 @131072
// ([64][68] f32) | sL @148480. SMSZ=150528.
// ---------------------------------------------------------------------------
#define W4OFF 131072
#define SLOFF 148480
#define SMSZ 150528

__global__ __launch_bounds__(1024, 4) void k2_attn_fused(
    const unsigned short* __restrict__ x1t,
    const unsigned short* __restrict__ x2t,
    const unsigned short* __restrict__ x3,
    const float* __restrict__ W4, const float* __restrict__ b4,
    const float* __restrict__ x, float* __restrict__ out) {
  __shared__ __align__(16) char SM[SMSZ];
  char* smB = (char*)SM;

  const int t = threadIdx.x;
  const int wave = t >> 6, lane = t & 63;
  const int l15 = lane & 15, lh = lane >> 4;
  const int split = wave >> 2, msub = wave & 3;
  const int b = blockIdx.x >> 5;
  const int m0 = (blockIdx.x & 31) << 7;
  const int nb = split * 1024; // this split's n-range, 32 steps of 32n

  const char* x1B = (const char*)(x1t + (size_t)b * 4096 * 64); // [n][c] 128B rows
  const char* x3B = (const char*)(x3 + (size_t)b * 64 * 4096);  // [c][n] 8192B rows
  const unsigned short* x2b = x2t + (size_t)b * 4096 * 64;

  { // W4 -> LDS transposed (region disjoint from staging and cO main use)
    float* Wt4 = (float*)(smB + W4OFF);
    for (int e = t; e < 4096; e += 1024) Wt4[(e & 63) * 68 + (e >> 6)] = W4[e];
  }

  // split-shared staging: SB + p*8192 = [K 4KB | V 4KB]
  char* SB = smB + split * 16384;

  // staging source offsets (R10-proven pre-swizzle), my share: i = msub
  int kSrc, vSrc;
  {
    const int o = msub * 1024 + lane * 16;
    const int n = o >> 7, cb = (o & 127) ^ ((n & 7) << 4);
    kSrc = n * 128 + cb; // + nt*128
    const int ch = o >> 7, rem = (o & 127) ^ ((ch & 7) << 4);
    vSrc = (ch * 2 + (rem >> 6)) * 8192 + (rem & 63); // + nt*2
  }

  // Q fragments (B-operand), persistent: 2 groups of 16 m (my 32-m slice)
  s16x8 qf[2][2];
#pragma unroll
  for (int q2 = 0; q2 < 2; ++q2) {
    const unsigned short* qp = x2b + (size_t)(m0 + msub * 32 + q2 * 16 + l15) * 64 + lh * 8;
    qf[q2][0] = *(const s16x8*)qp;
    qf[q2][1] = *(const s16x8*)(qp + 32);
  }

  f32x4 O[2][4];
#pragma unroll
  for (int q2 = 0; q2 < 2; ++q2)
#pragma unroll
    for (int s = 0; s < 4; ++s) O[q2][s] = (f32x4){0.f, 0.f, 0.f, 0.f};
  float l_part[2] = {0.f, 0.f};

  const int swzK = (l15 & 7) << 4;
  const int swzV = ((l15 >> 1) & 7) << 4;

  // prologue: each wave stages its share of tile 0 into buf0
  GLL16(x1B + (size_t)nb * 128 + kSrc, SB + msub * 1024);
  GLL16(x3B + (size_t)nb * 2 + vSrc, SB + 4096 + msub * 1024);
  __syncthreads(); // implicit vmcnt(0): tile 0 fully staged, all waves

  for (int j = 0; j < 32; ++j) {
    const int p = j & 1;
    // ---- issue next tile into buf p^1 (read-safe: its readers retired at
    //      the previous end-barrier); full-step shadow before the drain.
    if (j < 31) {
      const int nt = nb + (j + 1) * 32;
      char* DB = SB + (p ^ 1) * 8192;
      GLL16(x1B + (size_t)nt * 128 + kSrc, DB + msub * 1024);
      GLL16(x3B + (size_t)nt * 2 + vSrc, DB + 4096 + msub * 1024);
    }
    // ---- fragment reads from buf p
    const char* KB = SB + p * 8192;
    const char* VB = KB + 4096;
    s16x8 kf[2][2];
#pragma unroll
    for (int s2 = 0; s2 < 2; ++s2) {
      const char* kp = KB + (s2 * 16 + l15) * 128;
      kf[s2][0] = *(const s16x8*)(kp + ((lh * 16) ^ swzK));
      kf[s2][1] = *(const s16x8*)(kp + ((lh * 16 + 64) ^ swzK));
    }
    s16x8 vf[4];
#pragma unroll
    for (int s = 0; s < 4; ++s) {
      const int c = s * 16 + l15;
      const char* vrow = VB + (c >> 1) * 128;
      const int nat_e = (c & 1) * 64 + lh * 8;
      const s16x4 ve = *(const s16x4*)(vrow + (nat_e ^ swzV));
      const s16x4 vo = *(const s16x4*)(vrow + ((nat_e + 32) ^ swzV));
#pragma unroll
      for (int e = 0; e < 4; ++e) { vf[s][e] = ve[e]; vf[s][e + 4] = vo[e]; }
    }
    // ---- QK (K=32 over c) per q2, per 16n sub; exp2; transpose-free PV
#pragma unroll
    for (int q2 = 0; q2 < 2; ++q2) {
      f32x4 ze = {0.f, 0.f, 0.f, 0.f};
      ze = __builtin_amdgcn_mfma_f32_16x16x32_bf16(kf[0][0], qf[q2][0], ze, 0, 0, 0);
      ze = __builtin_amdgcn_mfma_f32_16x16x32_bf16(kf[0][1], qf[q2][1], ze, 0, 0, 0);
      f32x4 zo = {0.f, 0.f, 0.f, 0.f};
      zo = __builtin_amdgcn_mfma_f32_16x16x32_bf16(kf[1][0], qf[q2][0], zo, 0, 0, 0);
      zo = __builtin_amdgcn_mfma_f32_16x16x32_bf16(kf[1][1], qf[q2][1], zo, 0, 0, 0);
      const float e0 = __builtin_amdgcn_exp2f(ze[0]);
      const float e1 = __builtin_amdgcn_exp2f(ze[1]);
      const float e2 = __builtin_amdgcn_exp2f(ze[2]);
      const float e3 = __builtin_amdgcn_exp2f(ze[3]);
      const float o0 = __builtin_amdgcn_exp2f(zo[0]);
      const float o1 = __builtin_amdgcn_exp2f(zo[1]);
      const float o2 = __builtin_amdgcn_exp2f(zo[2]);
      const float o3 = __builtin_amdgcn_exp2f(zo[3]);
      l_part[q2] += ((e0 + e1) + (e2 + e3)) + ((o0 + o1) + (o2 + o3));
      int4 pw = {(int)packbf(e0, e1), (int)packbf(e2, e3),
                 (int)packbf(o0, o1), (int)packbf(o2, o3)};
      s16x8 pf = __builtin_bit_cast(s16x8, pw);
#pragma unroll
      for (int s = 0; s < 4; ++s)
        O[q2][s] = __builtin_amdgcn_mfma_f32_16x16x32_bf16(vf[s], pf, O[q2][s], 0, 0, 0);
    }
    __syncthreads(); // one barrier/step: reads of p done + all staging drained
  }

  // ---- epilogue 1: l reduce + publish fp32 partials (R13 swizzle, 8KB/wave)
  float* sLf = (float*)(smB + SLOFF); // [16][32]
#pragma unroll
  for (int q2 = 0; q2 < 2; ++q2) {
    const float l = redsum_lh(l_part[q2]);
    const int m32 = q2 * 16 + l15;
    if (lh == 0) sLf[wave * 32 + m32] = l;
#pragma unroll
    for (int s = 0; s < 4; ++s) {
      const int cb = s * 64 + lh * 16;
      *(f32x4*)(smB + wave * 8192 + m32 * 256 + (cb ^ ((m32 & 7) << 4))) = O[q2][s];
    }
  }
  __syncthreads();

  // ---- epilogue 2: merge 4 splits. thread -> m=t&127, channel group cq=t>>7
  const int mloc = t & 127, cq = t >> 7;
  const int msub2 = mloc >> 5, m32b = mloc & 31;
  float den = 0.f, num[8] = {0.f, 0.f, 0.f, 0.f, 0.f, 0.f, 0.f, 0.f};
#pragma unroll
  for (int s2 = 0; s2 < 4; ++s2) {
    const int w = s2 * 4 + msub2;
    den += sLf[w * 32 + m32b];
    const char* cw = smB + w * 8192 + m32b * 256;
#pragma unroll
    for (int h = 0; h < 2; ++h) {
      const f32x4 cv = *(const f32x4*)(cw + ((cq * 32 + h * 16) ^ ((m32b & 7) << 4)));
#pragma unroll
      for (int jj = 0; jj < 4; ++jj) num[h * 4 + jj] += cv[jj];
    }
  }
  const float inv = 1.f / den;
  __syncthreads(); // cO reads done -> overlay attnS
  float* attnS = (float*)smB; // [64][136]
#pragma unroll
  for (int jj = 0; jj < 8; ++jj) attnS[(cq * 8 + jj) * 136 + mloc] = num[jj] * inv;
  __syncthreads();

  // ---- epilogue 3: out = lrelu(W4 @ attn + b4) + x  (128 m per block)
  const float* Wt4 = (const float*)(smB + W4OFF); // [64][68]
  const int co0 = cq * 8;
  float acc[8];
#pragma unroll
  for (int ci = 0; ci < 8; ++ci) acc[ci] = b4[co0 + ci];
  for (int k = 0; k < 64; ++k) {
    const float a = attnS[k * 136 + mloc];
    const float4 w0 = *(const float4*)&Wt4[k * 68 + co0];
    const float4 w1 = *(const float4*)&Wt4[k * 68 + co0 + 4];
#pragma unroll
    for (int ci = 0; ci < 4; ++ci) {
      acc[ci] = __builtin_fmaf(((const float*)&w0)[ci], a, acc[ci]);
      acc[ci + 4] = __builtin_fmaf(((const float*)&w1)[ci], a, acc[ci + 4]);
    }
  }
#pragma unroll
  for (int ci = 0; ci < 8; ++ci) {
    const size_t idx = ((size_t)b * 64 + co0 + ci) * 4096 + m0 + mloc;
    out[idx] = lrelu(acc[ci]) + x[idx];
  }
}

extern "C" void kernel_launch(void* const* d_in, const int* in_sizes, int n_in,
                              void* d_out, int out_size, void* d_ws, size_t ws_size,
                              hipStream_t stream) {
  const float* x = (const float*)d_in[0];
  const float* W1 = (const float*)d_in[1];
  const float* b1 = (const float*)d_in[2];
  const float* W2 = (const float*)d_in[3];
  const float* b2 = (const float*)d_in[4];
  const float* W3 = (const float*)d_in[5];
  const float* b3 = (const float*)d_in[6];
  const float* W4 = (const float*)d_in[7];
  const float* b4 = (const float*)d_in[8];
  float* out = (float*)d_out;

  const size_t planes = (size_t)4 * 4096 * 64; // 1M bf16 elems each
  unsigned short* x1t = (unsigned short*)d_ws;
  unsigned short* x2t = x1t + planes;
  unsigned short* x3 = x2t + planes;
  float* WT = (float*)(x3 + planes); // 3*64*64 f32 = 48KB (ws is ~264MB)

  hipLaunchKernelGGL(k0_wt, dim3(3), dim3(256), 0, stream, W1, W2, W3, WT);
  hipLaunchKernelGGL(k1_conv3, dim3(512), dim3(256), 0, stream,
                     x, WT, b1, b2, b3, x1t, x2t, x3);
  hipLaunchKernelGGL(k2_attn_fused, dim3(128), dim3(1024), 0, stream,
                     x1t, x2t, x3, W4, b4, x, out);
}

// Round 15
// 77.855 us; speedup vs baseline: 1.4616x; 1.0093x over previous
//
#include <hip/hip_runtime.h>
#include <hip/hip_bf16.h>
#include <math.h>

using f32x4 = __attribute__((ext_vector_type(4))) float;
using s16x8 = __attribute__((ext_vector_type(8))) short;
using s16x4 = __attribute__((ext_vector_type(4))) short;

#define LOG2E 1.44269504f

__device__ __forceinline__ unsigned short f2bf(float f) {
  unsigned int u = __builtin_bit_cast(unsigned int, f);
  u += 0x7FFFu + ((u >> 16) & 1u);
  return (unsigned short)(u >> 16);
}
__device__ __forceinline__ float lrelu(float v) { return v > 0.f ? v : 0.01f * v; }

__device__ __forceinline__ unsigned packbf(float lo, float hi) {
  return __builtin_amdgcn_perm(__builtin_bit_cast(unsigned, hi),
                               __builtin_bit_cast(unsigned, lo), 0x07060302u);
}
__device__ __forceinline__ float redsum_lh(float x) {
  x += __shfl_xor(x, 16);
  x += __shfl_xor(x, 32);
  return x;
}

#define GLL16(src, dst)                                                        \
  __builtin_amdgcn_global_load_lds(                                            \
      (const __attribute__((address_space(1))) void*)(src),                    \
      (__attribute__((address_space(3))) void*)(dst), 16, 0, 0)

// ---------------------------------------------------------------------------
// Kernel 0: WT[w][k][c] = W_w[c][k]  (3x64x64 f32 into ws). grid 3, block 256.
// ---------------------------------------------------------------------------
__global__ __launch_bounds__(256) void k0_wt(const float* __restrict__ W1,
                                             const float* __restrict__ W2,
                                             const float* __restrict__ W3,
                                             float* __restrict__ WT) {
  __shared__ float s[64][65];
  const float* Ws[3] = {W1, W2, W3};
  const int w = blockIdx.x, t = threadIdx.x;
  for (int e = t; e < 4096; e += 256) s[e >> 6][e & 63] = Ws[w][e]; // s[c][k]
  __syncthreads();
  for (int e = t; e < 4096; e += 256) WT[w * 4096 + e] = s[e & 63][e >> 6];
}

// ---------------------------------------------------------------------------
// Kernel 1: x1t[n][c], x2t[n][c] (x2 pre-scaled by log2e), x3[c][n] (bf16).
// grid 512 (b*128 + nchunk32), block 512 (8 waves -> 16 waves/CU).
// ---------------------------------------------------------------------------
__global__ __launch_bounds__(512) void k1_conv3(
    const float* __restrict__ x, const float* __restrict__ WT,
    const float* __restrict__ b1, const float* __restrict__ b2,
    const float* __restrict__ b3,
    unsigned short* __restrict__ x1t, unsigned short* __restrict__ x2t,
    unsigned short* __restrict__ x3) {
  __shared__ float sB[64][33];
  const int t = threadIdx.x;
  const int b = blockIdx.x >> 7;
  const int n0 = (blockIdx.x & 127) << 5;
  const int c = t & 63, g = t >> 6; // wave g owns n' = g*4..g*4+3

  float y1[4], y2[4], y3[4];
  const float bb1 = b1[c], bb2 = b2[c], bb3 = b3[c];
#pragma unroll
  for (int j = 0; j < 4; ++j) { y1[j] = bb1; y2[j] = bb2; y3[j] = bb3; }

  const float* xb = x + ((size_t)b * 64) * 4096 + n0 + g * 4;
  const float* w1p = WT + c;
  const float* w2p = WT + 4096 + c;
  const float* w3p = WT + 8192 + c;
#pragma unroll 8
  for (int k = 0; k < 64; ++k) {
    const float w1 = w1p[k * 64], w2 = w2p[k * 64], w3 = w3p[k * 64];
    const float4 xv = *(const float4*)(xb + (size_t)k * 4096);
#pragma unroll
    for (int j = 0; j < 4; ++j) {
      const float xa = ((const float*)&xv)[j];
      y1[j] = __builtin_fmaf(w1, xa, y1[j]);
      y2[j] = __builtin_fmaf(w2, xa, y2[j]);
      y3[j] = __builtin_fmaf(w3, xa, y3[j]);
    }
  }
#pragma unroll
  for (int j = 0; j < 4; ++j) {
    const size_t n = (size_t)n0 + g * 4 + j;
    x1t[((size_t)b * 4096 + n) * 64 + c] = f2bf(lrelu(y1[j]));
    x2t[((size_t)b * 4096 + n) * 64 + c] = f2bf(lrelu(y2[j]) * LOG2E);
    sB[c][g * 4 + j] = lrelu(y3[j]);
  }
  __syncthreads();
  {
    const int c2 = t >> 3, q = t & 7;
    s16x4 v;
#pragma unroll
    for (int jj = 0; jj < 4; ++jj) v[jj] = (short)f2bf(sB[c2][q * 4 + jj]);
    *(s16x4*)(x3 + ((size_t)b * 64 + c2) * 4096 + n0 + q * 4) = v;
  }
}

// ---------------------------------------------------------------------------
// Kernel 2: flash attention slice (no-max exp2, transpose-free PV).
// grid 256 = (b:4, mtile:32 [128m], nhalf:2 [2048n]). block 1024 = 16 waves
// = split(4: 512n) x msub(4: 32m). 16 steps x 32n. Split-shared TRIPLE-buffer
// staging; per step: s_waitcnt vmcnt(2) -> s_barrier -> ds_read -> stage(j+2)
// -> compute. Loads never drained in-loop (T3/T4, m201 pattern).
// Epilogue: cO overlay (130KB over staging) merges 4 splits -> f32 partials
// + l to ws; k3 merges the 2 n-halves + conv4 + residual.
// LDS: staging 4 splits x 3 bufs x 8KB = 98304; epilogue cO 16x8KB = 131072
// + sL 2KB -> SMSZ 133120.
// ---------------------------------------------------------------------------
#define SLOFF2 131072
#define SMSZ2 133120

__global__ __launch_bounds__(1024, 4) void k2_attn(
    const unsigned short* __restrict__ x1t,
    const unsigned short* __restrict__ x2t,
    const unsigned short* __restrict__ x3,
    float* __restrict__ part, float* __restrict__ ml) {
  __shared__ __align__(16) char SM[SMSZ2];
  char* smB = (char*)SM;

  const int t = threadIdx.x;
  const int wave = t >> 6, lane = t & 63;
  const int l15 = lane & 15, lh = lane >> 4;
  const int split = wave >> 2, msub = wave & 3;
  const int blk = blockIdx.x;
  const int h = blk & 1, mt = (blk >> 1) & 31, b = blk >> 6;
  const int m0 = mt << 7;
  const int nb = h * 2048 + split * 512; // 16 steps of 32n

  const char* x1B = (const char*)(x1t + (size_t)b * 4096 * 64); // [n][c] 128B rows
  const char* x3B = (const char*)(x3 + (size_t)b * 64 * 4096);  // [c][n] 8192B rows
  const unsigned short* x2b = x2t + (size_t)b * 4096 * 64;

  // split-shared staging: 3 buffers of 8KB ([K 4KB | V 4KB])
  char* SB = smB + split * 24576;

  // staging source offsets (R10/R14-proven pre-swizzle); my share: i = msub
  int kSrc, vSrc;
  {
    const int o = msub * 1024 + lane * 16;
    const int n = o >> 7, cb = (o & 127) ^ ((n & 7) << 4);
    kSrc = n * 128 + cb; // + nt*128
    const int ch = o >> 7, rem = (o & 127) ^ ((ch & 7) << 4);
    vSrc = (ch * 2 + (rem >> 6)) * 8192 + (rem & 63); // + nt*2
  }

  // Q fragments (B-operand), persistent
  s16x8 qf[2][2];
#pragma unroll
  for (int q2 = 0; q2 < 2; ++q2) {
    const unsigned short* qp = x2b + (size_t)(m0 + msub * 32 + q2 * 16 + l15) * 64 + lh * 8;
    qf[q2][0] = *(const s16x8*)qp;
    qf[q2][1] = *(const s16x8*)(qp + 32);
  }

  f32x4 O[2][4];
#pragma unroll
  for (int q2 = 0; q2 < 2; ++q2)
#pragma unroll
    for (int s = 0; s < 4; ++s) O[q2][s] = (f32x4){0.f, 0.f, 0.f, 0.f};
  float l_part[2] = {0.f, 0.f};

  const int swzK = (l15 & 7) << 4;
  const int swzV = ((l15 >> 1) & 7) << 4;

  // prologue: stage tiles 0 -> buf0, 1 -> buf1 (2 GLL each per wave)
  {
    GLL16(x1B + (size_t)nb * 128 + kSrc, SB + msub * 1024);
    GLL16(x3B + (size_t)nb * 2 + vSrc, SB + 4096 + msub * 1024);
    const int n1 = nb + 32;
    GLL16(x1B + (size_t)n1 * 128 + kSrc, SB + 8192 + msub * 1024);
    GLL16(x3B + (size_t)n1 * 2 + vSrc, SB + 8192 + 4096 + msub * 1024);
  }

#pragma unroll
  for (int j = 0; j < 16; ++j) {
    // ---- my tile-j shares landed (2 newest = tile j+1); then block-wide sync
    if (j < 15) {
      asm volatile("s_waitcnt vmcnt(2)" ::: "memory");
    } else {
      asm volatile("s_waitcnt vmcnt(0)" ::: "memory");
    }
    __builtin_amdgcn_sched_barrier(0);
    __builtin_amdgcn_s_barrier(); // all waves waited -> tile j fully visible
    __builtin_amdgcn_sched_barrier(0);
    // ---- fragment reads from buf j%3 (static: loop fully unrolled)
    const char* KB = SB + (j % 3) * 8192;
    const char* VB = KB + 4096;
    s16x8 kf[2][2];
#pragma unroll
    for (int s2 = 0; s2 < 2; ++s2) {
      const char* kp = KB + (s2 * 16 + l15) * 128;
      kf[s2][0] = *(const s16x8*)(kp + ((lh * 16) ^ swzK));
      kf[s2][1] = *(const s16x8*)(kp + ((lh * 16 + 64) ^ swzK));
    }
    s16x8 vf[4];
#pragma unroll
    for (int s = 0; s < 4; ++s) {
      const int c = s * 16 + l15;
      const char* vrow = VB + (c >> 1) * 128;
      const int nat_e = (c & 1) * 64 + lh * 8;
      const s16x4 ve = *(const s16x4*)(vrow + (nat_e ^ swzV));
      const s16x4 vo = *(const s16x4*)(vrow + ((nat_e + 32) ^ swzV));
#pragma unroll
      for (int e = 0; e < 4; ++e) { vf[s][e] = ve[e]; vf[s][e + 4] = vo[e]; }
    }
    // ---- stage tile j+2 into buf (j+2)%3 (its readers passed the barrier)
    if (j < 14) {
      const int nt = nb + (j + 2) * 32;
      char* DB = SB + ((j + 2) % 3) * 8192;
      GLL16(x1B + (size_t)nt * 128 + kSrc, DB + msub * 1024);
      GLL16(x3B + (size_t)nt * 2 + vSrc, DB + 4096 + msub * 1024);
    }
    __builtin_amdgcn_sched_barrier(0);
    // ---- QK (2 x 16n subs) -> exp2 -> transpose-free PV (R12-proven)
#pragma unroll
    for (int q2 = 0; q2 < 2; ++q2) {
      f32x4 ze = {0.f, 0.f, 0.f, 0.f};
      ze = __builtin_amdgcn_mfma_f32_16x16x32_bf16(kf[0][0], qf[q2][0], ze, 0, 0, 0);
      ze = __builtin_amdgcn_mfma_f32_16x16x32_bf16(kf[0][1], qf[q2][1], ze, 0, 0, 0);
      f32x4 zo = {0.f, 0.f, 0.f, 0.f};
      zo = __builtin_amdgcn_mfma_f32_16x16x32_bf16(kf[1][0], qf[q2][0], zo, 0, 0, 0);
      zo = __builtin_amdgcn_mfma_f32_16x16x32_bf16(kf[1][1], qf[q2][1], zo, 0, 0, 0);
      const float e0 = __builtin_amdgcn_exp2f(ze[0]);
      const float e1 = __builtin_amdgcn_exp2f(ze[1]);
      const float e2 = __builtin_amdgcn_exp2f(ze[2]);
      const float e3 = __builtin_amdgcn_exp2f(ze[3]);
      const float o0 = __builtin_amdgcn_exp2f(zo[0]);
      const float o1 = __builtin_amdgcn_exp2f(zo[1]);
      const float o2 = __builtin_amdgcn_exp2f(zo[2]);
      const float o3 = __builtin_amdgcn_exp2f(zo[3]);
      l_part[q2] += ((e0 + e1) + (e2 + e3)) + ((o0 + o1) + (o2 + o3));
      int4 pw = {(int)packbf(e0, e1), (int)packbf(e2, e3),
                 (int)packbf(o0, o1), (int)packbf(o2, o3)};
      s16x8 pf = __builtin_bit_cast(s16x8, pw);
#pragma unroll
      for (int s = 0; s < 4; ++s)
        O[q2][s] = __builtin_amdgcn_mfma_f32_16x16x32_bf16(vf[s], pf, O[q2][s], 0, 0, 0);
    }
  }

  // ---- epilogue 1: l reduce + publish fp32 partials (R13 swizzle, 8KB/wave)
  __syncthreads(); // full drain; staging dead -> cO overlay safe
  float* sLf = (float*)(smB + SLOFF2); // [16][32]
#pragma unroll
  for (int q2 = 0; q2 < 2; ++q2) {
    const float l = redsum_lh(l_part[q2]);
    const int m32 = q2 * 16 + l15;
    if (lh == 0) sLf[wave * 32 + m32] = l;
#pragma unroll
    for (int s = 0; s < 4; ++s) {
      const int cb = s * 64 + lh * 16;
      *(f32x4*)(smB + wave * 8192 + m32 * 256 + (cb ^ ((m32 & 7) << 4))) = O[q2][s];
    }
  }
  __syncthreads();

  // ---- epilogue 2: merge 4 splits -> ws. thread -> m=t&127, cq=t>>7 (8 ch)
  const int mloc = t & 127, cq = t >> 7;
  const int msub2 = mloc >> 5, m32b = mloc & 31;
  float den = 0.f, num[8] = {0.f, 0.f, 0.f, 0.f, 0.f, 0.f, 0.f, 0.f};
#pragma unroll
  for (int s2 = 0; s2 < 4; ++s2) {
    const int w = s2 * 4 + msub2;
    den += sLf[w * 32 + m32b];
    const char* cw = smB + w * 8192 + m32b * 256;
#pragma unroll
    for (int hh = 0; hh < 2; ++hh) {
      const f32x4 cv = *(const f32x4*)(cw + ((cq * 32 + hh * 16) ^ ((m32b & 7) << 4)));
#pragma unroll
      for (int jj = 0; jj < 4; ++jj) num[hh * 4 + jj] += cv[jj];
    }
  }
  float* pb = part + (size_t)blk * 8192; // [64c][128m]
#pragma unroll
  for (int jj = 0; jj < 8; ++jj) pb[(cq * 8 + jj) * 128 + mloc] = num[jj];
  if (cq == 0) ml[(size_t)blk * 128 + mloc] = den;
}

// ---------------------------------------------------------------------------
// Kernel 3: merge 2 n-halves + conv4 + lrelu + residual.
// grid 512 = (b:4, mt4:128 [32m each]), block 256.
// ---------------------------------------------------------------------------
__global__ __launch_bounds__(256) void k3_merge_conv4(
    const float* __restrict__ part, const float* __restrict__ ml,
    const float* __restrict__ x, const float* __restrict__ W4,
    const float* __restrict__ b4, float* __restrict__ out) {
  __shared__ float attnS[64][33];
  __shared__ alignas(16) float Wt4[64][68];
  const int t = threadIdx.x;
  const int b = blockIdx.x >> 7, mt4 = blockIdx.x & 127;
  const int m0 = mt4 << 5;
  const int blk0 = (b * 32 + (mt4 >> 2)) * 2;
  const int moff = (mt4 & 3) * 32;

  for (int e = t; e < 4096; e += 256) Wt4[e & 63][e >> 6] = W4[e];
  {
    const int m = t & 31, cg = t >> 5; // 8 channels per thread
    const float den = ml[(size_t)blk0 * 128 + moff + m] +
                      ml[(size_t)(blk0 + 1) * 128 + moff + m];
    const float inv = 1.f / den;
    const float* p0 = part + (size_t)blk0 * 8192 + moff + m;
    const float* p1 = p0 + 8192;
#pragma unroll
    for (int ci = 0; ci < 8; ++ci) {
      const int c = cg * 8 + ci;
      attnS[c][m] = (p0[c * 128] + p1[c * 128]) * inv;
    }
  }
  __syncthreads();
  const int m = t & 31, cg = t >> 5;
  const int co0 = cg * 8;
  float acc[8];
#pragma unroll
  for (int ci = 0; ci < 8; ++ci) acc[ci] = b4[co0 + ci];
  for (int k = 0; k < 64; ++k) {
    const float a = attnS[k][m];
    const float4 w0 = *(const float4*)&Wt4[k][co0];
    const float4 w1 = *(const float4*)&Wt4[k][co0 + 4];
#pragma unroll
    for (int ci = 0; ci < 4; ++ci) {
      acc[ci] = __builtin_fmaf(((const float*)&w0)[ci], a, acc[ci]);
      acc[ci + 4] = __builtin_fmaf(((const float*)&w1)[ci], a, acc[ci + 4]);
    }
  }
#pragma unroll
  for (int ci = 0; ci < 8; ++ci) {
    const size_t idx = ((size_t)b * 64 + co0 + ci) * 4096 + m0 + m;
    out[idx] = lrelu(acc[ci]) + x[idx];
  }
}

extern "C" void kernel_launch(void* const* d_in, const int* in_sizes, int n_in,
                              void* d_out, int out_size, void* d_ws, size_t ws_size,
                              hipStream_t stream) {
  const float* x = (const float*)d_in[0];
  const float* W1 = (const float*)d_in[1];
  const float* b1 = (const float*)d_in[2];
  const float* W2 = (const float*)d_in[3];
  const float* b2 = (const float*)d_in[4];
  const float* W3 = (const float*)d_in[5];
  const float* b3 = (const float*)d_in[6];
  const float* W4 = (const float*)d_in[7];
  const float* b4 = (const float*)d_in[8];
  float* out = (float*)d_out;

  const size_t planes = (size_t)4 * 4096 * 64; // 1M bf16 elems each
  unsigned short* x1t = (unsigned short*)d_ws;
  unsigned short* x2t = x1t + planes;
  unsigned short* x3 = x2t + planes;
  float* part = (float*)(x3 + planes);        // 256*64*128 f32 = 8MB
  float* ml = part + (size_t)256 * 8192;      // 256*128 f32 = 128KB
  float* WT = ml + 256 * 128;                 // 3*4096 f32 = 48KB

  hipLaunchKernelGGL(k0_wt, dim3(3), dim3(256), 0, stream, W1, W2, W3, WT);
  hipLaunchKernelGGL(k1_conv3, dim3(512), dim3(512), 0, stream,
                     x, WT, b1, b2, b3, x1t, x2t, x3);
  hipLaunchKernelGGL(k2_attn, dim3(256), dim3(1024), 0, stream,
                     x1t, x2t, x3, part, ml);
  hipLaunchKernelGGL(k3_merge_conv4, dim3(512), dim3(256), 0, stream,
                     part, ml, x, W4, b4, out);
}